// Round 1
// baseline (7288.708 us; speedup 1.0000x reference)
//
#include <hip/hip_runtime.h>
#include <math.h>

// Problem constants (AttentionOCR): B=512, P=64, CIN=512, HID=512, EMB=512, NCLS=96, T=30
static constexpr int BATCH = 512;
static constexpr int PPOS  = 64;
static constexpr int HIDC  = 512;
static constexpr int NCLSC = 96;

static __device__ __forceinline__ float sigmoidf_(float x) { return 1.f / (1.f + expf(-x)); }

// ---------------- transpose: dst[C x R] = src[R x C]^T ----------------
__global__ void transpose_k(const float* __restrict__ src, float* __restrict__ dst, int R, int C) {
  __shared__ float tile[32][33];
  int c0 = blockIdx.x * 32, r0 = blockIdx.y * 32;
  int x = threadIdx.x;
  for (int yy = threadIdx.y; yy < 32; yy += 8) {
    int r = r0 + yy, c = c0 + x;
    if (r < R && c < C) tile[yy][x] = src[(size_t)r * C + c];
  }
  __syncthreads();
  for (int yy = threadIdx.y; yy < 32; yy += 8) {
    int c = c0 + yy, r = r0 + x;
    if (r < R && c < C) dst[(size_t)c * R + r] = tile[x][yy];
  }
}

// ---------------- generic fp32 GEMM: C[MxN] = A[MxK] @ B[KxN] (+bias) ----------------
// BM=BN=64, BK=16, 256 threads, 4x4 micro-tile. Requires M%64==0, N%64==0, K%16==0.
template <bool BIAS>
__global__ __launch_bounds__(256) void gemm64_k(const float* __restrict__ A, const float* __restrict__ Bm,
                                                const float* __restrict__ bias, float* __restrict__ C,
                                                int M, int N, int K) {
  __shared__ float As[16][68];
  __shared__ float Bs[16][64];
  int tid = threadIdx.x;
  int tx = tid & 15, ty = tid >> 4;
  int row0 = blockIdx.y * 64, col0 = blockIdx.x * 64;
  float acc[4][4] = {};
  for (int k0 = 0; k0 < K; k0 += 16) {
    {
      int r = tid >> 2;
      int kk = (tid & 3) * 4;
      float4 v = *(const float4*)(A + (size_t)(row0 + r) * K + k0 + kk);
      As[kk + 0][r] = v.x; As[kk + 1][r] = v.y; As[kk + 2][r] = v.z; As[kk + 3][r] = v.w;
    }
    {
      int n = tid & 63, kb = tid >> 6;
#pragma unroll
      for (int i = 0; i < 4; i++)
        Bs[kb + i * 4][n] = Bm[(size_t)(k0 + kb + i * 4) * N + col0 + n];
    }
    __syncthreads();
#pragma unroll
    for (int q = 0; q < 16; q++) {
      float a0 = As[q][ty * 4 + 0], a1 = As[q][ty * 4 + 1], a2 = As[q][ty * 4 + 2], a3 = As[q][ty * 4 + 3];
      float b0 = Bs[q][tx * 4 + 0], b1 = Bs[q][tx * 4 + 1], b2 = Bs[q][tx * 4 + 2], b3 = Bs[q][tx * 4 + 3];
      acc[0][0] += a0 * b0; acc[0][1] += a0 * b1; acc[0][2] += a0 * b2; acc[0][3] += a0 * b3;
      acc[1][0] += a1 * b0; acc[1][1] += a1 * b1; acc[1][2] += a1 * b2; acc[1][3] += a1 * b3;
      acc[2][0] += a2 * b0; acc[2][1] += a2 * b1; acc[2][2] += a2 * b2; acc[2][3] += a2 * b3;
      acc[3][0] += a3 * b0; acc[3][1] += a3 * b1; acc[3][2] += a3 * b2; acc[3][3] += a3 * b3;
    }
    __syncthreads();
  }
#pragma unroll
  for (int i = 0; i < 4; i++)
#pragma unroll
    for (int j = 0; j < 4; j++) {
      int rr = row0 + ty * 4 + i, cc = col0 + tx * 4 + j;
      float v = acc[i][j];
      if (BIAS) v += bias[cc];
      C[(size_t)rr * N + cc] = v;
    }
}

// ---------------- bfused[n] = bih[n] + bhh[n] + dot(Wih[n,:], bc) ----------------
__global__ void bfuse_k(const float* __restrict__ Wih, const float* __restrict__ bc,
                        const float* __restrict__ bih, const float* __restrict__ bhh,
                        float* __restrict__ bf) {
  int n = blockIdx.x * 256 + threadIdx.x;  // < 2048
  float s = bih[n] + bhh[n];
  const float* w = Wih + (size_t)n * 512;
  for (int m = 0; m < 512; m++) s += w[m] * bc[m];
  bf[n] = s;
}

// ---------------- per-step attn logits: z[B,512] = [h | emb] @ WaT + ba ----------------
// BM=32, BN=64, grid (8,16)
__global__ __launch_bounds__(256) void attn_z_k(const float* __restrict__ h_prev, const float* __restrict__ emb_table,
                                                const int* __restrict__ targets, int t, int T,
                                                const float* __restrict__ WaT, const float* __restrict__ ba,
                                                float* __restrict__ z) {
  __shared__ float As[16][33];
  __shared__ float Bs[16][64];
  int tid = threadIdx.x;
  int tx = tid & 15, ty = tid >> 4;
  int row0 = blockIdx.y * 32, col0 = blockIdx.x * 64;
  float acc[2][4] = {};
  for (int k0 = 0; k0 < 1024; k0 += 16) {
    {
      int r = tid >> 3;            // 0..31
      int kk = (tid & 7) * 2;      // even
      int bb = row0 + r;
      int k = k0 + kk;
      float v0, v1;
      if (k0 < 512) {
        v0 = h_prev[(size_t)bb * 512 + k];
        v1 = h_prev[(size_t)bb * 512 + k + 1];
      } else {
        int id = (t == 0) ? 0 : targets[bb * T + t - 1];
        v0 = emb_table[(size_t)id * 512 + (k - 512)];
        v1 = emb_table[(size_t)id * 512 + (k - 511)];
      }
      As[kk][r] = v0;
      As[kk + 1][r] = v1;
    }
    {
      int n = tid & 63, kb = tid >> 6;
#pragma unroll
      for (int i = 0; i < 4; i++)
        Bs[kb + i * 4][n] = WaT[(size_t)(k0 + kb + i * 4) * 512 + col0 + n];
    }
    __syncthreads();
#pragma unroll
    for (int q = 0; q < 16; q++) {
      float a0 = As[q][ty * 2], a1 = As[q][ty * 2 + 1];
      float b0 = Bs[q][tx * 4], b1 = Bs[q][tx * 4 + 1], b2 = Bs[q][tx * 4 + 2], b3 = Bs[q][tx * 4 + 3];
      acc[0][0] += a0 * b0; acc[0][1] += a0 * b1; acc[0][2] += a0 * b2; acc[0][3] += a0 * b3;
      acc[1][0] += a1 * b0; acc[1][1] += a1 * b1; acc[1][2] += a1 * b2; acc[1][3] += a1 * b3;
    }
    __syncthreads();
  }
#pragma unroll
  for (int i = 0; i < 2; i++)
#pragma unroll
    for (int j = 0; j < 4; j++) {
      int rr = row0 + ty * 2 + i, cc = col0 + tx * 4 + j;
      z[(size_t)rr * 512 + cc] = acc[i][j] + ba[cc];
    }
}

// ---------------- softmax over hid (rows of 512), one wave per row ----------------
__global__ void softmax_a_k(const float* __restrict__ z, float* __restrict__ a) {
  int b = blockIdx.x;
  int l = threadIdx.x;  // 64
  float v[8];
  float m = -1e30f;
#pragma unroll
  for (int j = 0; j < 8; j++) {
    v[j] = z[(size_t)b * 512 + l + 64 * j];
    m = fmaxf(m, v[j]);
  }
#pragma unroll
  for (int off = 32; off; off >>= 1) m = fmaxf(m, __shfl_xor(m, off, 64));
  float s = 0.f;
#pragma unroll
  for (int j = 0; j < 8; j++) { v[j] = expf(v[j] - m); s += v[j]; }
#pragma unroll
  for (int off = 32; off; off >>= 1) s += __shfl_xor(s, off, 64);
  float inv = 1.f / s;
#pragma unroll
  for (int j = 0; j < 8; j++) a[(size_t)b * 512 + l + 64 * j] = v[j] * inv;
}

// ---------------- attention: scores -> softmax(P=64) -> ctx, one block per batch row ----------------
__global__ __launch_bounds__(256) void attn_ctx_k(const float* __restrict__ feats, const float* __restrict__ a,
                                                  float* __restrict__ ctx) {
  __shared__ float a_s[512];
  __shared__ float sc_s[64];
  __shared__ float w_s[64];
  int b = blockIdx.x;
  int tid = threadIdx.x;
  a_s[tid] = a[(size_t)b * 512 + tid];
  a_s[tid + 256] = a[(size_t)b * 512 + tid + 256];
  __syncthreads();
  int wave = tid >> 6, lane = tid & 63;
  const float* fb = feats + (size_t)b * PPOS * 512;
  for (int p = wave; p < 64; p += 4) {
    const float* fp = fb + (size_t)p * 512;
    float d = 0.f;
#pragma unroll
    for (int j = 0; j < 8; j++) d += fp[lane + 64 * j] * a_s[lane + 64 * j];
#pragma unroll
    for (int off = 32; off; off >>= 1) d += __shfl_xor(d, off, 64);
    if (lane == 0) sc_s[p] = d;
  }
  __syncthreads();
  if (tid < 64) {
    float s = sc_s[tid];
    float m = s;
#pragma unroll
    for (int off = 32; off; off >>= 1) m = fmaxf(m, __shfl_xor(m, off, 64));
    float e = expf(s - m);
    float sum = e;
#pragma unroll
    for (int off = 32; off; off >>= 1) sum += __shfl_xor(sum, off, 64);
    w_s[tid] = e / sum;
  }
  __syncthreads();
#pragma unroll 1
  for (int h0 = tid; h0 < 512; h0 += 256) {
    float acc = 0.f;
#pragma unroll
    for (int p = 0; p < 64; p++) acc += w_s[p] * fb[(size_t)p * 512 + h0];
    ctx[(size_t)b * 512 + h0] = acc;
  }
}

// ---------------- gates GEMM: gates[B,2048] = [emb|ctx|h] @ Bcat[1536x2048] + bf ----------------
// BM=BN=64, grid (32, 8)
__global__ __launch_bounds__(256) void gates_k(const float* __restrict__ h_prev, const float* __restrict__ ctx,
                                               const float* __restrict__ emb_table, const int* __restrict__ targets,
                                               int t, int T,
                                               const float* __restrict__ Bcat, const float* __restrict__ bf,
                                               float* __restrict__ gates) {
  __shared__ float As[16][68];
  __shared__ float Bs[16][64];
  int tid = threadIdx.x;
  int tx = tid & 15, ty = tid >> 4;
  int row0 = blockIdx.y * 64, col0 = blockIdx.x * 64;
  float acc[4][4] = {};
  for (int k0 = 0; k0 < 1536; k0 += 16) {
    {
      int r = tid >> 2;
      int kk = (tid & 3) * 4;
      int bb = row0 + r;
      int k = k0 + kk;
      float4 v;
      if (k0 < 512) {
        int id = (t == 0) ? 0 : targets[bb * T + t - 1];
        v = *(const float4*)(emb_table + (size_t)id * 512 + k);
      } else if (k0 < 1024) {
        v = *(const float4*)(ctx + (size_t)bb * 512 + (k - 512));
      } else {
        v = *(const float4*)(h_prev + (size_t)bb * 512 + (k - 1024));
      }
      As[kk + 0][r] = v.x; As[kk + 1][r] = v.y; As[kk + 2][r] = v.z; As[kk + 3][r] = v.w;
    }
    {
      int n = tid & 63, kb = tid >> 6;
#pragma unroll
      for (int i = 0; i < 4; i++)
        Bs[kb + i * 4][n] = Bcat[(size_t)(k0 + kb + i * 4) * 2048 + col0 + n];
    }
    __syncthreads();
#pragma unroll
    for (int q = 0; q < 16; q++) {
      float a0 = As[q][ty * 4 + 0], a1 = As[q][ty * 4 + 1], a2 = As[q][ty * 4 + 2], a3 = As[q][ty * 4 + 3];
      float b0 = Bs[q][tx * 4 + 0], b1 = Bs[q][tx * 4 + 1], b2 = Bs[q][tx * 4 + 2], b3 = Bs[q][tx * 4 + 3];
      acc[0][0] += a0 * b0; acc[0][1] += a0 * b1; acc[0][2] += a0 * b2; acc[0][3] += a0 * b3;
      acc[1][0] += a1 * b0; acc[1][1] += a1 * b1; acc[1][2] += a1 * b2; acc[1][3] += a1 * b3;
      acc[2][0] += a2 * b0; acc[2][1] += a2 * b1; acc[2][2] += a2 * b2; acc[2][3] += a2 * b3;
      acc[3][0] += a3 * b0; acc[3][1] += a3 * b1; acc[3][2] += a3 * b2; acc[3][3] += a3 * b3;
    }
    __syncthreads();
  }
#pragma unroll
  for (int i = 0; i < 4; i++)
#pragma unroll
    for (int j = 0; j < 4; j++) {
      int rr = row0 + ty * 4 + i, cc = col0 + tx * 4 + j;
      gates[(size_t)rr * 2048 + cc] = acc[i][j] + bf[cc];
    }
}

// ---------------- LSTM pointwise ----------------
__global__ void lstm_pw_k(const float* __restrict__ gates, float* __restrict__ c, float* __restrict__ h_out) {
  int idx = blockIdx.x * 256 + threadIdx.x;  // < B*HID
  int b = idx >> 9, j = idx & 511;
  const float* g = gates + (size_t)b * 2048;
  float ig = sigmoidf_(g[j]);
  float fg = sigmoidf_(g[512 + j]);
  float gg = tanhf(g[1024 + j]);
  float og = sigmoidf_(g[1536 + j]);
  float cn = fg * c[idx] + ig * gg;
  float hn = og * tanhf(cn);
  c[idx] = cn;
  h_out[idx] = hn;
}

// ---------------- final output GEMM over all timesteps ----------------
// C[T*B x 96] = h_hist @ WoT + bo, scattered to out[b, t, n]. BM=64, grid 240.
__global__ __launch_bounds__(256) void out_gemm_k(const float* __restrict__ h_hist, const float* __restrict__ WoT,
                                                  const float* __restrict__ bo, float* __restrict__ out, int T) {
  __shared__ float As[16][68];
  __shared__ float Bs[16][96];
  int tid = threadIdx.x;
  int tx = tid & 15, ty = tid >> 4;
  int row0 = blockIdx.x * 64;
  float acc[4][6] = {};
  for (int k0 = 0; k0 < 512; k0 += 16) {
    {
      int r = tid >> 2;
      int kk = (tid & 3) * 4;
      float4 v = *(const float4*)(h_hist + (size_t)(row0 + r) * 512 + k0 + kk);
      As[kk + 0][r] = v.x; As[kk + 1][r] = v.y; As[kk + 2][r] = v.z; As[kk + 3][r] = v.w;
    }
#pragma unroll
    for (int i = 0; i < 6; i++) {
      int e = tid + 256 * i;
      int kb = e / 96, n = e - kb * 96;
      Bs[kb][n] = WoT[(size_t)(k0 + kb) * 96 + n];
    }
    __syncthreads();
#pragma unroll
    for (int q = 0; q < 16; q++) {
      float av[4], bv[6];
#pragma unroll
      for (int i = 0; i < 4; i++) av[i] = As[q][ty * 4 + i];
#pragma unroll
      for (int j = 0; j < 6; j++) bv[j] = Bs[q][tx * 6 + j];
#pragma unroll
      for (int i = 0; i < 4; i++)
#pragma unroll
        for (int j = 0; j < 6; j++) acc[i][j] += av[i] * bv[j];
    }
    __syncthreads();
  }
#pragma unroll
  for (int i = 0; i < 4; i++)
#pragma unroll
    for (int j = 0; j < 6; j++) {
      int row = row0 + ty * 4 + i;
      int tt = row >> 9, bb = row & 511;
      int cc = tx * 6 + j;
      out[((size_t)bb * T + tt) * 96 + cc] = acc[i][j] + bo[cc];
    }
}

extern "C" void kernel_launch(void* const* d_in, const int* in_sizes, int n_in,
                              void* d_out, int out_size, void* d_ws, size_t ws_size,
                              hipStream_t stream) {
  const float* features  = (const float*)d_in[0];
  const int*   targets   = (const int*)d_in[1];
  const float* Wfc       = (const float*)d_in[3];
  const float* bfc       = (const float*)d_in[4];
  const float* emb_table = (const float*)d_in[5];
  const float* Wa        = (const float*)d_in[6];
  const float* ba        = (const float*)d_in[7];
  const float* Wc        = (const float*)d_in[8];
  const float* bc        = (const float*)d_in[9];
  const float* Wih       = (const float*)d_in[10];
  const float* Whh       = (const float*)d_in[11];
  const float* bih       = (const float*)d_in[12];
  const float* bhh       = (const float*)d_in[13];
  const float* Wo        = (const float*)d_in[14];
  const float* bo        = (const float*)d_in[15];
  float* out = (float*)d_out;
  int T = in_sizes[1] / BATCH;  // 30

  float* ws = (float*)d_ws;
  float* feats  = ws; ws += (size_t)BATCH * PPOS * HIDC;   // 16.8M
  float* WfcT   = ws; ws += 512 * 512;
  float* WaT    = ws; ws += 1024 * 512;
  float* WcT    = ws; ws += 1024 * 512;
  float* WihT   = ws; ws += 512 * 2048;
  float* Bcat   = ws; ws += (size_t)1536 * 2048;           // rows 0..1023 = WfT, 1024..1535 = WhhT
  float* WoT    = ws; ws += 512 * 96;
  float* bf     = ws; ws += 2048;
  float* h0     = ws; ws += BATCH * HIDC;
  float* cbuf   = ws; ws += BATCH * HIDC;
  float* z      = ws; ws += BATCH * HIDC;
  float* a      = ws; ws += BATCH * HIDC;
  float* ctx    = ws; ws += BATCH * HIDC;
  float* gates  = ws; ws += (size_t)BATCH * 2048;
  float* h_hist = ws; ws += (size_t)T * BATCH * HIDC;      // 7.9M

  dim3 tb(32, 8);
  // Pre-transposed weights
  transpose_k<<<dim3(16, 16), tb, 0, stream>>>(Wfc, WfcT, 512, 512);
  transpose_k<<<dim3(32, 16), tb, 0, stream>>>(Wa, WaT, 512, 1024);
  transpose_k<<<dim3(32, 16), tb, 0, stream>>>(Wc, WcT, 512, 1024);
  transpose_k<<<dim3(16, 64), tb, 0, stream>>>(Wih, WihT, 2048, 512);
  transpose_k<<<dim3(16, 64), tb, 0, stream>>>(Whh, Bcat + (size_t)1024 * 2048, 2048, 512);
  transpose_k<<<dim3(16, 3), tb, 0, stream>>>(Wo, WoT, 96, 512);

  // feats = features @ Wfc.T + bfc   [32768 x 512]
  gemm64_k<true><<<dim3(512 / 64, 32768 / 64), 256, 0, stream>>>(features, WfcT, bfc, feats, 32768, 512, 512);
  // WfT = WcT @ WihT  [1024 x 2048]  (fused Wih@Wc, stored K-major)
  gemm64_k<false><<<dim3(2048 / 64, 1024 / 64), 256, 0, stream>>>(WcT, WihT, nullptr, Bcat, 1024, 2048, 512);
  bfuse_k<<<8, 256, 0, stream>>>(Wih, bc, bih, bhh, bf);
  hipMemsetAsync(h0, 0, (size_t)BATCH * HIDC * sizeof(float), stream);
  hipMemsetAsync(cbuf, 0, (size_t)BATCH * HIDC * sizeof(float), stream);

  for (int t = 0; t < T; t++) {
    const float* h_prev = (t == 0) ? h0 : (h_hist + (size_t)(t - 1) * BATCH * HIDC);
    float* h_new = h_hist + (size_t)t * BATCH * HIDC;
    attn_z_k<<<dim3(8, 16), 256, 0, stream>>>(h_prev, emb_table, targets, t, T, WaT, ba, z);
    softmax_a_k<<<BATCH, 64, 0, stream>>>(z, a);
    attn_ctx_k<<<BATCH, 256, 0, stream>>>(feats, a, ctx);
    gates_k<<<dim3(2048 / 64, 512 / 64), 256, 0, stream>>>(h_prev, ctx, emb_table, targets, t, T, Bcat, bf, gates);
    lstm_pw_k<<<(BATCH * HIDC) / 256, 256, 0, stream>>>(gates, cbuf, h_new);
  }
  out_gemm_k<<<(T * BATCH) / 64, 256, 0, stream>>>(h_hist, WoT, bo, out, T);
}

// Round 2
// 3710.184 us; speedup vs baseline: 1.9645x; 1.9645x over previous
//
#include <hip/hip_runtime.h>
#include <math.h>

// AttentionOCR: B=512, P=64, CIN=512, HID=512, EMB=512, NCLS=96, T=30
static constexpr int BATCH = 512;
static constexpr int PPOS  = 64;
static constexpr int HIDC  = 512;

static __device__ __forceinline__ float sigmoidf_(float x) { return 1.f / (1.f + expf(-x)); }

// ---------------- strided transpose: dst[C x R], dst[c][r] = src[r*ld + c] ----------------
__global__ void transpose_k(const float* __restrict__ src, float* __restrict__ dst, int R, int C, int ld) {
  __shared__ float tile[32][33];
  int c0 = blockIdx.x * 32, r0 = blockIdx.y * 32;
  int x = threadIdx.x;
  for (int yy = threadIdx.y; yy < 32; yy += 8) {
    int r = r0 + yy, c = c0 + x;
    if (r < R && c < C) tile[yy][x] = src[(size_t)r * ld + c];
  }
  __syncthreads();
  for (int yy = threadIdx.y; yy < 32; yy += 8) {
    int c = c0 + yy, r = r0 + x;
    if (r < R && c < C) dst[(size_t)c * R + r] = tile[x][yy];
  }
}

// ---------------- generic fp32 GEMM: C[MxN] = A[MxK] @ B[KxN] (+bias); M%64==0,N%64==0,K%16==0 ----------------
template <bool BIAS>
__global__ __launch_bounds__(256) void gemm64_k(const float* __restrict__ A, const float* __restrict__ Bm,
                                                const float* __restrict__ bias, float* __restrict__ C,
                                                int M, int N, int K) {
  __shared__ float As[16][68];
  __shared__ float Bs[16][64];
  int tid = threadIdx.x;
  int tx = tid & 15, ty = tid >> 4;
  int row0 = blockIdx.y * 64, col0 = blockIdx.x * 64;
  float acc[4][4] = {};
  for (int k0 = 0; k0 < K; k0 += 16) {
    {
      int r = tid >> 2;
      int kk = (tid & 3) * 4;
      float4 v = *(const float4*)(A + (size_t)(row0 + r) * K + k0 + kk);
      As[kk + 0][r] = v.x; As[kk + 1][r] = v.y; As[kk + 2][r] = v.z; As[kk + 3][r] = v.w;
    }
    {
      int n = tid & 63, kb = tid >> 6;
#pragma unroll
      for (int i = 0; i < 4; i++)
        Bs[kb + i * 4][n] = Bm[(size_t)(k0 + kb + i * 4) * N + col0 + n];
    }
    __syncthreads();
#pragma unroll
    for (int q = 0; q < 16; q++) {
      float a0 = As[q][ty * 4 + 0], a1 = As[q][ty * 4 + 1], a2 = As[q][ty * 4 + 2], a3 = As[q][ty * 4 + 3];
      float b0 = Bs[q][tx * 4 + 0], b1 = Bs[q][tx * 4 + 1], b2 = Bs[q][tx * 4 + 2], b3 = Bs[q][tx * 4 + 3];
      acc[0][0] += a0 * b0; acc[0][1] += a0 * b1; acc[0][2] += a0 * b2; acc[0][3] += a0 * b3;
      acc[1][0] += a1 * b0; acc[1][1] += a1 * b1; acc[1][2] += a1 * b2; acc[1][3] += a1 * b3;
      acc[2][0] += a2 * b0; acc[2][1] += a2 * b1; acc[2][2] += a2 * b2; acc[2][3] += a2 * b3;
      acc[3][0] += a3 * b0; acc[3][1] += a3 * b1; acc[3][2] += a3 * b2; acc[3][3] += a3 * b3;
    }
    __syncthreads();
  }
#pragma unroll
  for (int i = 0; i < 4; i++)
#pragma unroll
    for (int j = 0; j < 4; j++) {
      int rr = row0 + ty * 4 + i, cc = col0 + tx * 4 + j;
      float v = acc[i][j];
      if (BIAS) v += bias[cc];
      C[(size_t)rr * N + cc] = v;
    }
}

// ---------------- bfused[n] = bih[n] + bhh[n] + dot(Wih[n,:], bc) ----------------
__global__ void bfuse_k(const float* __restrict__ Wih, const float* __restrict__ bc,
                        const float* __restrict__ bih, const float* __restrict__ bhh,
                        float* __restrict__ bf) {
  int n = blockIdx.x * 256 + threadIdx.x;  // < 2048
  float s = bih[n] + bhh[n];
  const float* w = Wih + (size_t)n * 512;
  for (int m = 0; m < 512; m++) s += w[m] * bc[m];
  bf[n] = s;
}

// ---------------- Bcat[1024 x 2048], gate-interleaved columns ----------------
// k<512: ctx part = tmp[512+k][n];  k>=512: h part = Whh[n][k-512];  col' = j*4+g, n = g*512+j
__global__ void build_bcat_k(const float* __restrict__ tmp, const float* __restrict__ Whh,
                             float* __restrict__ Bcat) {
  int idx = blockIdx.x * 256 + threadIdx.x;  // < 1024*2048
  int k = idx >> 11;
  int cp = idx & 2047;
  int j = cp >> 2, g = cp & 3;
  int n = g * 512 + j;
  float v = (k < 512) ? tmp[(size_t)(512 + k) * 2048 + n] : Whh[(size_t)n * 512 + (k - 512)];
  Bcat[idx] = v;
}

// ---------------- Gemb_p[96 x 2048] = (emb_table @ tmp[0:512]) + bfused, columns permuted ----------------
__global__ __launch_bounds__(256) void gemb_k(const float* __restrict__ emb_table, const float* __restrict__ tmp,
                                              const float* __restrict__ bfused, float* __restrict__ Gemb_p) {
  __shared__ float emb_s[4][512];
  int tid = threadIdx.x;
  int n0 = blockIdx.x * 256;      // 8 blocks
  int e0 = blockIdx.y * 4;        // 24 blocks
  for (int i = tid; i < 2048; i += 256)
    emb_s[i >> 9][i & 511] = emb_table[(size_t)(e0 + (i >> 9)) * 512 + (i & 511)];
  __syncthreads();
  int n = n0 + tid;
  float acc[4] = {};
  for (int k = 0; k < 512; k++) {
    float w = tmp[(size_t)k * 2048 + n];
#pragma unroll
    for (int e = 0; e < 4; e++) acc[e] += emb_s[e][k] * w;
  }
  int cp = (n & 511) * 4 + (n >> 9);
  float b = bfused[n];
#pragma unroll
  for (int e = 0; e < 4; e++) Gemb_p[(size_t)(e0 + e) * 2048 + cp] = acc[e] + b;
}

// ---------------- Za[96 x 512] = emb_table @ WaT_emb + ba ----------------
__global__ __launch_bounds__(256) void za_k(const float* __restrict__ emb_table, const float* __restrict__ WaT_emb,
                                            const float* __restrict__ ba, float* __restrict__ Za) {
  __shared__ float emb_s[4][512];
  int tid = threadIdx.x;
  int n0 = blockIdx.x * 256;      // 2 blocks
  int e0 = blockIdx.y * 4;        // 24 blocks
  for (int i = tid; i < 2048; i += 256)
    emb_s[i >> 9][i & 511] = emb_table[(size_t)(e0 + (i >> 9)) * 512 + (i & 511)];
  __syncthreads();
  int n = n0 + tid;
  float acc[4] = {};
  for (int k = 0; k < 512; k++) {
    float w = WaT_emb[(size_t)k * 512 + n];
#pragma unroll
    for (int e = 0; e < 4; e++) acc[e] += emb_s[e][k] * w;
  }
  float b = ba[n];
#pragma unroll
  for (int e = 0; e < 4; e++) Za[(size_t)(e0 + e) * 512 + n] = acc[e] + b;
}

// ---------------- fused attention step: z -> softmax(hid) -> scores -> softmax(P) -> ctx ----------------
// 2 batch rows per block, 256 blocks, 512 threads.
__global__ __launch_bounds__(512) void attn_fused_k(const float* __restrict__ h_prev,
                                                    const int* __restrict__ targets, int t, int T,
                                                    const float* __restrict__ WaT_h, const float* __restrict__ Za,
                                                    const float* __restrict__ feats, float* __restrict__ ctx) {
  __shared__ __align__(16) float h_s[2][512];
  __shared__ __align__(16) float z_s[2][512];
  __shared__ float red0[8], red1[8];
  __shared__ float sc_s[2][64];
  __shared__ float w_s[2][64];
  int tid = threadIdx.x;
  int wid = tid >> 6, lane = tid & 63;
  int b0 = blockIdx.x * 2;
  int id0 = (t == 0) ? 0 : targets[b0 * T + t - 1];
  int id1 = (t == 0) ? 0 : targets[(b0 + 1) * T + t - 1];
  for (int i = tid; i < 1024; i += 512)
    h_s[i >> 9][i & 511] = h_prev[(size_t)(b0 + (i >> 9)) * 512 + (i & 511)];
  __syncthreads();

  // --- z for n = tid ---
  float acc0 = Za[(size_t)id0 * 512 + tid];
  float acc1 = Za[(size_t)id1 * 512 + tid];
#pragma unroll 8
  for (int k = 0; k < 512; k++) {
    float w = WaT_h[(size_t)k * 512 + tid];
    acc0 += h_s[0][k] * w;
    acc1 += h_s[1][k] * w;
  }

  // --- softmax over 512 (per row) ---
  float m0 = acc0, m1 = acc1;
#pragma unroll
  for (int off = 32; off; off >>= 1) {
    m0 = fmaxf(m0, __shfl_xor(m0, off, 64));
    m1 = fmaxf(m1, __shfl_xor(m1, off, 64));
  }
  if (lane == 0) { red0[wid] = m0; red1[wid] = m1; }
  __syncthreads();
  float M0 = red0[0], M1 = red1[0];
#pragma unroll
  for (int i = 1; i < 8; i++) { M0 = fmaxf(M0, red0[i]); M1 = fmaxf(M1, red1[i]); }
  __syncthreads();
  float e0 = expf(acc0 - M0), e1 = expf(acc1 - M1);
  float s0 = e0, s1 = e1;
#pragma unroll
  for (int off = 32; off; off >>= 1) {
    s0 += __shfl_xor(s0, off, 64);
    s1 += __shfl_xor(s1, off, 64);
  }
  if (lane == 0) { red0[wid] = s0; red1[wid] = s1; }
  __syncthreads();
  float S0 = 0.f, S1 = 0.f;
#pragma unroll
  for (int i = 0; i < 8; i++) { S0 += red0[i]; S1 += red1[i]; }
  z_s[0][tid] = e0 / S0;
  z_s[1][tid] = e1 / S1;
  __syncthreads();

  // --- scores: 128 tasks (r,p), 16 per wave ---
#pragma unroll 1
  for (int q = 0; q < 16; q++) {
    int task = wid * 16 + q;
    int r = task >> 6, p = task & 63;
    const float4* fp = (const float4*)(feats + ((size_t)(b0 + r) * PPOS + p) * 512);
    const float4* ap = (const float4*)(z_s[r]);
    float4 f1 = fp[lane], a1 = ap[lane];
    float4 f2 = fp[lane + 64], a2 = ap[lane + 64];
    float d = f1.x * a1.x + f1.y * a1.y + f1.z * a1.z + f1.w * a1.w
            + f2.x * a2.x + f2.y * a2.y + f2.z * a2.z + f2.w * a2.w;
#pragma unroll
    for (int off = 32; off; off >>= 1) d += __shfl_xor(d, off, 64);
    if (lane == 0) sc_s[r][p] = d;
  }
  __syncthreads();

  // --- softmax over P=64 (wave 0 -> row 0, wave 1 -> row 1) ---
  if (tid < 128) {
    int r = wid;
    float v = sc_s[r][lane];
    float m = v;
#pragma unroll
    for (int off = 32; off; off >>= 1) m = fmaxf(m, __shfl_xor(m, off, 64));
    float e = expf(v - m);
    float s = e;
#pragma unroll
    for (int off = 32; off; off >>= 1) s += __shfl_xor(s, off, 64);
    w_s[r][lane] = e / s;
  }
  __syncthreads();

  // --- ctx ---
#pragma unroll 1
  for (int r = 0; r < 2; r++) {
    const float* fb = feats + (size_t)(b0 + r) * PPOS * 512 + tid;
    float acc = 0.f;
#pragma unroll 8
    for (int p = 0; p < 64; p++) acc += w_s[r][p] * fb[(size_t)p * 512];
    ctx[(size_t)(b0 + r) * 512 + tid] = acc;
  }
}

// ---------------- gates GEMM (K=1024, [ctx|h]) + Gemb gather + LSTM pointwise epilogue ----------------
// BM=32, BN=64, grid (32,16) = 512 blocks, 256 threads. Bcat columns gate-interleaved.
__global__ __launch_bounds__(256) void gates_lstm_k(const float* __restrict__ ctx, const float* __restrict__ h_prev,
                                                    const int* __restrict__ targets, int t, int T,
                                                    const float* __restrict__ Bcat, const float* __restrict__ Gemb_p,
                                                    float* __restrict__ cbuf, float* __restrict__ h_new) {
  __shared__ float As[16][36];
  __shared__ float Bs[16][64];
  int tid = threadIdx.x;
  int tx = tid & 15, ty = tid >> 4;
  int row0 = blockIdx.y * 32, col0 = blockIdx.x * 64;
  float acc[2][4] = {};
  for (int k0 = 0; k0 < 1024; k0 += 16) {
    {
      int r = tid >> 3;          // 0..31
      int kk = (tid & 7) * 2;
      const float* srcA = (k0 < 512) ? (ctx + (size_t)(row0 + r) * 512 + k0 + kk)
                                     : (h_prev + (size_t)(row0 + r) * 512 + (k0 - 512) + kk);
      float2 av = *(const float2*)srcA;
      As[kk][r] = av.x; As[kk + 1][r] = av.y;
    }
    {
      int n = tid & 63, kb = tid >> 6;
#pragma unroll
      for (int i = 0; i < 4; i++)
        Bs[kb + 4 * i][n] = Bcat[(size_t)(k0 + kb + 4 * i) * 2048 + col0 + n];
    }
    __syncthreads();
#pragma unroll
    for (int q = 0; q < 16; q++) {
      float a0 = As[q][ty * 2], a1 = As[q][ty * 2 + 1];
      float4 b = *(const float4*)&Bs[q][tx * 4];
      acc[0][0] += a0 * b.x; acc[0][1] += a0 * b.y; acc[0][2] += a0 * b.z; acc[0][3] += a0 * b.w;
      acc[1][0] += a1 * b.x; acc[1][1] += a1 * b.y; acc[1][2] += a1 * b.z; acc[1][3] += a1 * b.w;
    }
    __syncthreads();
  }
  int j = (col0 >> 2) + tx;
#pragma unroll
  for (int i = 0; i < 2; i++) {
    int b = row0 + ty * 2 + i;
    int id = (t == 0) ? 0 : targets[b * T + t - 1];
    float4 g4 = *(const float4*)(Gemb_p + (size_t)id * 2048 + j * 4);
    float ig = sigmoidf_(acc[i][0] + g4.x);
    float fg = sigmoidf_(acc[i][1] + g4.y);
    float gg = tanhf(acc[i][2] + g4.z);
    float og = sigmoidf_(acc[i][3] + g4.w);
    float cn = fg * cbuf[(size_t)b * 512 + j] + ig * gg;
    float hn = og * tanhf(cn);
    cbuf[(size_t)b * 512 + j] = cn;
    h_new[(size_t)b * 512 + j] = hn;
  }
}

// ---------------- final output GEMM over all timesteps ----------------
__global__ __launch_bounds__(256) void out_gemm_k(const float* __restrict__ h_hist, const float* __restrict__ WoT,
                                                  const float* __restrict__ bo, float* __restrict__ out, int T) {
  __shared__ float As[16][68];
  __shared__ float Bs[16][96];
  int tid = threadIdx.x;
  int tx = tid & 15, ty = tid >> 4;
  int row0 = blockIdx.x * 64;
  float acc[4][6] = {};
  for (int k0 = 0; k0 < 512; k0 += 16) {
    {
      int r = tid >> 2;
      int kk = (tid & 3) * 4;
      float4 v = *(const float4*)(h_hist + (size_t)(row0 + r) * 512 + k0 + kk);
      As[kk + 0][r] = v.x; As[kk + 1][r] = v.y; As[kk + 2][r] = v.z; As[kk + 3][r] = v.w;
    }
#pragma unroll
    for (int i = 0; i < 6; i++) {
      int e = tid + 256 * i;
      int kb = e / 96, n = e - kb * 96;
      Bs[kb][n] = WoT[(size_t)(k0 + kb) * 96 + n];
    }
    __syncthreads();
#pragma unroll
    for (int q = 0; q < 16; q++) {
      float av[4], bv[6];
#pragma unroll
      for (int i = 0; i < 4; i++) av[i] = As[q][ty * 4 + i];
#pragma unroll
      for (int j = 0; j < 6; j++) bv[j] = Bs[q][tx * 6 + j];
#pragma unroll
      for (int i = 0; i < 4; i++)
#pragma unroll
        for (int j = 0; j < 6; j++) acc[i][j] += av[i] * bv[j];
    }
    __syncthreads();
  }
#pragma unroll
  for (int i = 0; i < 4; i++)
#pragma unroll
    for (int j = 0; j < 6; j++) {
      int row = row0 + ty * 4 + i;
      int tt = row >> 9, bb = row & 511;
      int cc = tx * 6 + j;
      out[((size_t)bb * T + tt) * 96 + cc] = acc[i][j] + bo[cc];
    }
}

extern "C" void kernel_launch(void* const* d_in, const int* in_sizes, int n_in,
                              void* d_out, int out_size, void* d_ws, size_t ws_size,
                              hipStream_t stream) {
  const float* features  = (const float*)d_in[0];
  const int*   targets   = (const int*)d_in[1];
  const float* Wfc       = (const float*)d_in[3];
  const float* bfc       = (const float*)d_in[4];
  const float* emb_table = (const float*)d_in[5];
  const float* Wa        = (const float*)d_in[6];
  const float* ba        = (const float*)d_in[7];
  const float* Wc        = (const float*)d_in[8];
  const float* bc        = (const float*)d_in[9];
  const float* Wih       = (const float*)d_in[10];
  const float* Whh       = (const float*)d_in[11];
  const float* bih       = (const float*)d_in[12];
  const float* bhh       = (const float*)d_in[13];
  const float* Wo        = (const float*)d_in[14];
  const float* bo        = (const float*)d_in[15];
  float* out = (float*)d_out;
  int T = in_sizes[1] / BATCH;  // 30

  float* ws = (float*)d_ws;
  float* feats   = ws; ws += (size_t)BATCH * PPOS * HIDC;   // 16.8M
  float* WfcT    = ws; ws += 512 * 512;
  float* WaT_h   = ws; ws += 512 * 512;
  float* WaT_emb = ws; ws += 512 * 512;
  float* WcT     = ws; ws += 1024 * 512;
  float* WihT    = ws; ws += 512 * 2048;
  float* tmp     = ws; ws += (size_t)1024 * 2048;           // Wbig^T
  float* Bcat    = ws; ws += (size_t)1024 * 2048;           // gate-interleaved
  float* Gemb_p  = ws; ws += 96 * 2048;
  float* Za      = ws; ws += 96 * 512;
  float* bfused  = ws; ws += 2048;
  float* WoT     = ws; ws += 512 * 96;
  float* h0      = ws; ws += BATCH * HIDC;
  float* cbuf    = ws; ws += BATCH * HIDC;
  float* ctx     = ws; ws += BATCH * HIDC;
  float* h_hist  = ws; ws += (size_t)T * BATCH * HIDC;      // 7.9M

  dim3 tb(32, 8);
  transpose_k<<<dim3(16, 16), tb, 0, stream>>>(Wfc, WfcT, 512, 512, 512);
  transpose_k<<<dim3(16, 16), tb, 0, stream>>>(Wa, WaT_h, 512, 512, 1024);
  transpose_k<<<dim3(16, 16), tb, 0, stream>>>(Wa + 512, WaT_emb, 512, 512, 1024);
  transpose_k<<<dim3(32, 16), tb, 0, stream>>>(Wc, WcT, 512, 1024, 1024);
  transpose_k<<<dim3(16, 64), tb, 0, stream>>>(Wih, WihT, 2048, 512, 512);
  transpose_k<<<dim3(16, 3),  tb, 0, stream>>>(Wo, WoT, 96, 512, 512);

  // tmp = WcT[1024x512] @ WihT[512x2048]  ( = (Wih@Wc)^T )
  gemm64_k<false><<<dim3(32, 16), 256, 0, stream>>>(WcT, WihT, nullptr, tmp, 1024, 2048, 512);
  bfuse_k<<<8, 256, 0, stream>>>(Wih, bc, bih, bhh, bfused);
  build_bcat_k<<<(1024 * 2048) / 256, 256, 0, stream>>>(tmp, Whh, Bcat);
  gemb_k<<<dim3(8, 24), 256, 0, stream>>>(emb_table, tmp, bfused, Gemb_p);
  za_k<<<dim3(2, 24), 256, 0, stream>>>(emb_table, WaT_emb, ba, Za);

  // feats = features @ Wfc.T + bfc   [32768 x 512]
  gemm64_k<true><<<dim3(8, 512), 256, 0, stream>>>(features, WfcT, bfc, feats, 32768, 512, 512);

  hipMemsetAsync(h0, 0, (size_t)BATCH * HIDC * sizeof(float), stream);
  hipMemsetAsync(cbuf, 0, (size_t)BATCH * HIDC * sizeof(float), stream);

  for (int t = 0; t < T; t++) {
    const float* h_prev = (t == 0) ? h0 : (h_hist + (size_t)(t - 1) * BATCH * HIDC);
    float* h_new = h_hist + (size_t)t * BATCH * HIDC;
    attn_fused_k<<<256, 512, 0, stream>>>(h_prev, targets, t, T, WaT_h, Za, feats, ctx);
    gates_lstm_k<<<dim3(32, 16), 256, 0, stream>>>(ctx, h_prev, targets, t, T, Bcat, Gemb_p, cbuf, h_new);
  }
  out_gemm_k<<<(T * BATCH) / 64, 256, 0, stream>>>(h_hist, WoT, bo, out, T);
}

// Round 3
// 3077.776 us; speedup vs baseline: 2.3682x; 1.2055x over previous
//
#include <hip/hip_runtime.h>
#include <math.h>

// AttentionOCR: B=512, P=64, CIN=512, HID=512, EMB=512, NCLS=96, T=30
static constexpr int BATCH = 512;
static constexpr int PPOS  = 64;
static constexpr int HIDC  = 512;

static __device__ __forceinline__ float sigmoidf_(float x) { return 1.f / (1.f + expf(-x)); }

// ---------------- strided transpose: dst[C x R], dst[c][r] = src[r*ld + c] ----------------
__global__ void transpose_k(const float* __restrict__ src, float* __restrict__ dst, int R, int C, int ld) {
  __shared__ float tile[32][33];
  int c0 = blockIdx.x * 32, r0 = blockIdx.y * 32;
  int x = threadIdx.x;
  for (int yy = threadIdx.y; yy < 32; yy += 8) {
    int r = r0 + yy, c = c0 + x;
    if (r < R && c < C) tile[yy][x] = src[(size_t)r * ld + c];
  }
  __syncthreads();
  for (int yy = threadIdx.y; yy < 32; yy += 8) {
    int c = c0 + yy, r = r0 + x;
    if (r < R && c < C) dst[(size_t)c * R + r] = tile[x][yy];
  }
}

// ---- fp32 GEMM: C[MxN]=A[MxK]@B[KxN](+bias). BM=BN=64, BK=16, 256 thr, 4x4 micro,
// ---- register-prefetch double-buffer, ONE barrier per K-tile.
template <bool BIAS>
__global__ __launch_bounds__(256) void gemm64_k(const float* __restrict__ A, const float* __restrict__ Bm,
                                                const float* __restrict__ bias, float* __restrict__ C,
                                                int M, int N, int K) {
  __shared__ float As[2][16][68];
  __shared__ float Bs[2][16][64];
  int tid = threadIdx.x;
  int tx = tid & 15, ty = tid >> 4;
  int row0 = blockIdx.y * 64, col0 = blockIdx.x * 64;
  int ar = tid >> 2, ak = (tid & 3) * 4;      // A stage: row ar, cols ak..ak+3
  int bkb = tid >> 4, bn = (tid & 15) * 4;    // B stage: row bkb, cols bn..bn+3
  const float* Aptr = A + (size_t)(row0 + ar) * K + ak;
  const float* Bptr = Bm + (size_t)bkb * N + col0 + bn;
  float4 av = *(const float4*)Aptr;
  float4 bv = *(const float4*)Bptr;
  float acc[4][4] = {};
  int NT = K / 16;
  for (int kt = 0; kt < NT; kt++) {
    int buf = kt & 1;
    As[buf][ak + 0][ar] = av.x; As[buf][ak + 1][ar] = av.y;
    As[buf][ak + 2][ar] = av.z; As[buf][ak + 3][ar] = av.w;
    *(float4*)&Bs[buf][bkb][bn] = bv;
    if (kt + 1 < NT) {
      Aptr += 16; Bptr += (size_t)16 * N;
      av = *(const float4*)Aptr;
      bv = *(const float4*)Bptr;
    }
    __syncthreads();
#pragma unroll
    for (int q = 0; q < 16; q++) {
      float4 a4 = *(const float4*)&As[buf][q][ty * 4];
      float4 b4 = *(const float4*)&Bs[buf][q][tx * 4];
      acc[0][0] += a4.x * b4.x; acc[0][1] += a4.x * b4.y; acc[0][2] += a4.x * b4.z; acc[0][3] += a4.x * b4.w;
      acc[1][0] += a4.y * b4.x; acc[1][1] += a4.y * b4.y; acc[1][2] += a4.y * b4.z; acc[1][3] += a4.y * b4.w;
      acc[2][0] += a4.z * b4.x; acc[2][1] += a4.z * b4.y; acc[2][2] += a4.z * b4.z; acc[2][3] += a4.z * b4.w;
      acc[3][0] += a4.w * b4.x; acc[3][1] += a4.w * b4.y; acc[3][2] += a4.w * b4.z; acc[3][3] += a4.w * b4.w;
    }
  }
#pragma unroll
  for (int i = 0; i < 4; i++)
#pragma unroll
    for (int j = 0; j < 4; j++) {
      int rr = row0 + ty * 4 + i, cc = col0 + tx * 4 + j;
      float v = acc[i][j];
      if (BIAS) v += bias[cc];
      C[(size_t)rr * N + cc] = v;
    }
}

// ---------------- bfused[n] = bih[n] + bhh[n] + dot(Wih[n,:], bc) ----------------
__global__ void bfuse_k(const float* __restrict__ Wih, const float* __restrict__ bc,
                        const float* __restrict__ bih, const float* __restrict__ bhh,
                        float* __restrict__ bf) {
  int n = blockIdx.x * 256 + threadIdx.x;  // < 2048
  float s = bih[n] + bhh[n];
  const float* w = Wih + (size_t)n * 512;
  for (int m = 0; m < 512; m++) s += w[m] * bc[m];
  bf[n] = s;
}

// ---------------- Bcat[1024 x 2048], gate-interleaved columns ----------------
__global__ void build_bcat_k(const float* __restrict__ tmp, const float* __restrict__ Whh,
                             float* __restrict__ Bcat) {
  int idx = blockIdx.x * 256 + threadIdx.x;  // < 1024*2048
  int k = idx >> 11;
  int cp = idx & 2047;
  int j = cp >> 2, g = cp & 3;
  int n = g * 512 + j;
  float v = (k < 512) ? tmp[(size_t)(512 + k) * 2048 + n] : Whh[(size_t)n * 512 + (k - 512)];
  Bcat[idx] = v;
}

// ---------------- Gemb_p[96 x 2048] = (emb_table @ tmp[0:512]) + bfused, columns permuted ----------------
__global__ __launch_bounds__(256) void gemb_k(const float* __restrict__ emb_table, const float* __restrict__ tmp,
                                              const float* __restrict__ bfused, float* __restrict__ Gemb_p) {
  __shared__ float emb_s[4][512];
  int tid = threadIdx.x;
  int n0 = blockIdx.x * 256;
  int e0 = blockIdx.y * 4;
  for (int i = tid; i < 2048; i += 256)
    emb_s[i >> 9][i & 511] = emb_table[(size_t)(e0 + (i >> 9)) * 512 + (i & 511)];
  __syncthreads();
  int n = n0 + tid;
  float acc[4] = {};
  for (int k = 0; k < 512; k++) {
    float w = tmp[(size_t)k * 2048 + n];
#pragma unroll
    for (int e = 0; e < 4; e++) acc[e] += emb_s[e][k] * w;
  }
  int cp = (n & 511) * 4 + (n >> 9);
  float b = bfused[n];
#pragma unroll
  for (int e = 0; e < 4; e++) Gemb_p[(size_t)(e0 + e) * 2048 + cp] = acc[e] + b;
}

// ---------------- Za[96 x 512] = emb_table @ WaT_emb + ba ----------------
__global__ __launch_bounds__(256) void za_k(const float* __restrict__ emb_table, const float* __restrict__ WaT_emb,
                                            const float* __restrict__ ba, float* __restrict__ Za) {
  __shared__ float emb_s[4][512];
  int tid = threadIdx.x;
  int n0 = blockIdx.x * 256;
  int e0 = blockIdx.y * 4;
  for (int i = tid; i < 2048; i += 256)
    emb_s[i >> 9][i & 511] = emb_table[(size_t)(e0 + (i >> 9)) * 512 + (i & 511)];
  __syncthreads();
  int n = n0 + tid;
  float acc[4] = {};
  for (int k = 0; k < 512; k++) {
    float w = WaT_emb[(size_t)k * 512 + n];
#pragma unroll
    for (int e = 0; e < 4; e++) acc[e] += emb_s[e][k] * w;
  }
  float b = ba[n];
#pragma unroll
  for (int e = 0; e < 4; e++) Za[(size_t)(e0 + e) * 512 + n] = acc[e] + b;
}

// ---------------- fused attention step: z -> softmax(hid) -> scores -> softmax(P) -> ctx ----------------
// 2 batch rows per block, 256 blocks, 512 threads. z-phase: split-K x4, float4 weight loads.
__global__ __launch_bounds__(512) void attn_fused_k(const float* __restrict__ h_prev,
                                                    const int* __restrict__ targets, int t, int T,
                                                    const float* __restrict__ WaT_h, const float* __restrict__ Za,
                                                    const float* __restrict__ feats, float* __restrict__ ctx) {
  __shared__ __align__(16) float h_s[2][512];
  __shared__ __align__(16) float zred[4][2][512];   // 16 KB split-K partials
  __shared__ __align__(16) float z_s[2][512];
  __shared__ float redm[8], reds[8];
  __shared__ float sc_s[2][64];
  __shared__ float w_s[2][64];
  int tid = threadIdx.x;
  int wid = tid >> 6, lane = tid & 63;
  int b0 = blockIdx.x * 2;
  int id0 = (t == 0) ? 0 : targets[b0 * T + t - 1];
  int id1 = (t == 0) ? 0 : targets[(b0 + 1) * T + t - 1];
  for (int i = tid; i < 1024; i += 512)
    h_s[i >> 9][i & 511] = h_prev[(size_t)(b0 + (i >> 9)) * 512 + (i & 511)];
  __syncthreads();

  // --- z partials: thread (nq, ks): cols nq*4..+3, k-range ks*128..+127 ---
  {
    int nq = tid & 127, ks = tid >> 7;
    int n0 = nq * 4;
    const float* wb = WaT_h + (size_t)(ks * 128) * 512 + n0;
    float a00 = 0.f, a01 = 0.f, a02 = 0.f, a03 = 0.f;
    float a10 = 0.f, a11 = 0.f, a12 = 0.f, a13 = 0.f;
#pragma unroll 4
    for (int k = 0; k < 128; k++) {
      float4 w = *(const float4*)(wb + (size_t)k * 512);
      float hv0 = h_s[0][ks * 128 + k];
      float hv1 = h_s[1][ks * 128 + k];
      a00 += hv0 * w.x; a01 += hv0 * w.y; a02 += hv0 * w.z; a03 += hv0 * w.w;
      a10 += hv1 * w.x; a11 += hv1 * w.y; a12 += hv1 * w.z; a13 += hv1 * w.w;
    }
    *(float4*)&zred[ks][0][n0] = make_float4(a00, a01, a02, a03);
    *(float4*)&zred[ks][1][n0] = make_float4(a10, a11, a12, a13);
  }
  __syncthreads();

  // --- reduce + softmax over hid (row r: threads tid>>8==r, 4 waves, 2 vals each) ---
  {
    int r = tid >> 8;
    int nn = tid & 255;
    int idr = r ? id1 : id0;
    float zv0 = Za[(size_t)idr * 512 + nn]
              + zred[0][r][nn] + zred[1][r][nn] + zred[2][r][nn] + zred[3][r][nn];
    float zv1 = Za[(size_t)idr * 512 + nn + 256]
              + zred[0][r][nn + 256] + zred[1][r][nn + 256] + zred[2][r][nn + 256] + zred[3][r][nn + 256];
    float m = fmaxf(zv0, zv1);
#pragma unroll
    for (int off = 32; off; off >>= 1) m = fmaxf(m, __shfl_xor(m, off, 64));
    if (lane == 0) redm[wid] = m;
    __syncthreads();
    float M = fmaxf(fmaxf(redm[r * 4], redm[r * 4 + 1]), fmaxf(redm[r * 4 + 2], redm[r * 4 + 3]));
    float e0 = expf(zv0 - M), e1 = expf(zv1 - M);
    float s = e0 + e1;
#pragma unroll
    for (int off = 32; off; off >>= 1) s += __shfl_xor(s, off, 64);
    if (lane == 0) reds[wid] = s;
    __syncthreads();
    float S = reds[r * 4] + reds[r * 4 + 1] + reds[r * 4 + 2] + reds[r * 4 + 3];
    float inv = 1.f / S;
    z_s[r][nn] = e0 * inv;
    z_s[r][nn + 256] = e1 * inv;
  }
  __syncthreads();

  // --- scores: 128 tasks (r,p), 16 per wave ---
#pragma unroll 1
  for (int q = 0; q < 16; q++) {
    int task = wid * 16 + q;
    int r = task >> 6, p = task & 63;
    const float4* fp = (const float4*)(feats + ((size_t)(b0 + r) * PPOS + p) * 512);
    const float4* ap = (const float4*)(z_s[r]);
    float4 f1 = fp[lane], a1 = ap[lane];
    float4 f2 = fp[lane + 64], a2 = ap[lane + 64];
    float d = f1.x * a1.x + f1.y * a1.y + f1.z * a1.z + f1.w * a1.w
            + f2.x * a2.x + f2.y * a2.y + f2.z * a2.z + f2.w * a2.w;
#pragma unroll
    for (int off = 32; off; off >>= 1) d += __shfl_xor(d, off, 64);
    if (lane == 0) sc_s[r][p] = d;
  }
  __syncthreads();

  // --- softmax over P=64 ---
  if (tid < 128) {
    int r = wid;
    float v = sc_s[r][lane];
    float m = v;
#pragma unroll
    for (int off = 32; off; off >>= 1) m = fmaxf(m, __shfl_xor(m, off, 64));
    float e = expf(v - m);
    float s = e;
#pragma unroll
    for (int off = 32; off; off >>= 1) s += __shfl_xor(s, off, 64);
    w_s[r][lane] = e / s;
  }
  __syncthreads();

  // --- ctx ---
#pragma unroll 1
  for (int r = 0; r < 2; r++) {
    const float* fb = feats + (size_t)(b0 + r) * PPOS * 512 + tid;
    float acc = 0.f;
#pragma unroll 8
    for (int p = 0; p < 64; p++) acc += w_s[r][p] * fb[(size_t)p * 512];
    ctx[(size_t)(b0 + r) * 512 + tid] = acc;
  }
}

// ---------------- gates GEMM (K=1024, [ctx|h]) + Gemb gather + LSTM pointwise epilogue ----------------
// BM=64, BN=64, grid (32,8)=256 blocks, 256 thr, 4x4 micro, double-buffered, 1 barrier/tile.
__global__ __launch_bounds__(256) void gates_lstm_k(const float* __restrict__ ctx, const float* __restrict__ h_prev,
                                                    const int* __restrict__ targets, int t, int T,
                                                    const float* __restrict__ Bcat, const float* __restrict__ Gemb_p,
                                                    float* __restrict__ cbuf, float* __restrict__ h_new) {
  __shared__ float As[2][16][68];
  __shared__ float Bs[2][16][64];
  int tid = threadIdx.x;
  int tx = tid & 15, ty = tid >> 4;
  int row0 = blockIdx.y * 64, col0 = blockIdx.x * 64;
  int ar = tid >> 2, ak = (tid & 3) * 4;
  int bkb = tid >> 4, bn = (tid & 15) * 4;
  const float* arow_c = ctx + (size_t)(row0 + ar) * 512;
  const float* arow_h = h_prev + (size_t)(row0 + ar) * 512;
  const float* Bptr = Bcat + (size_t)bkb * 2048 + col0 + bn;
  float4 av = *(const float4*)(arow_c + ak);
  float4 bv = *(const float4*)Bptr;
  float acc[4][4] = {};
  for (int kt = 0; kt < 64; kt++) {
    int buf = kt & 1;
    As[buf][ak + 0][ar] = av.x; As[buf][ak + 1][ar] = av.y;
    As[buf][ak + 2][ar] = av.z; As[buf][ak + 3][ar] = av.w;
    *(float4*)&Bs[buf][bkb][bn] = bv;
    if (kt + 1 < 64) {
      int kcol = (kt + 1) * 16 + ak;
      av = (kcol < 512) ? *(const float4*)(arow_c + kcol) : *(const float4*)(arow_h + (kcol - 512));
      Bptr += (size_t)16 * 2048;
      bv = *(const float4*)Bptr;
    }
    __syncthreads();
#pragma unroll
    for (int q = 0; q < 16; q++) {
      float4 a4 = *(const float4*)&As[buf][q][ty * 4];
      float4 b4 = *(const float4*)&Bs[buf][q][tx * 4];
      acc[0][0] += a4.x * b4.x; acc[0][1] += a4.x * b4.y; acc[0][2] += a4.x * b4.z; acc[0][3] += a4.x * b4.w;
      acc[1][0] += a4.y * b4.x; acc[1][1] += a4.y * b4.y; acc[1][2] += a4.y * b4.z; acc[1][3] += a4.y * b4.w;
      acc[2][0] += a4.z * b4.x; acc[2][1] += a4.z * b4.y; acc[2][2] += a4.z * b4.z; acc[2][3] += a4.z * b4.w;
      acc[3][0] += a4.w * b4.x; acc[3][1] += a4.w * b4.y; acc[3][2] += a4.w * b4.z; acc[3][3] += a4.w * b4.w;
    }
  }
  int j = (col0 >> 2) + tx;   // hidden unit (gate-interleaved cols)
#pragma unroll
  for (int i = 0; i < 4; i++) {
    int b = row0 + ty * 4 + i;
    int id = (t == 0) ? 0 : targets[b * T + t - 1];
    float4 g4 = *(const float4*)(Gemb_p + (size_t)id * 2048 + j * 4);
    float ig = sigmoidf_(acc[i][0] + g4.x);
    float fg = sigmoidf_(acc[i][1] + g4.y);
    float gg = tanhf(acc[i][2] + g4.z);
    float og = sigmoidf_(acc[i][3] + g4.w);
    float cn = fg * cbuf[(size_t)b * 512 + j] + ig * gg;
    float hn = og * tanhf(cn);
    cbuf[(size_t)b * 512 + j] = cn;
    h_new[(size_t)b * 512 + j] = hn;
  }
}

// ---------------- final output GEMM over all timesteps ----------------
__global__ __launch_bounds__(256) void out_gemm_k(const float* __restrict__ h_hist, const float* __restrict__ WoT,
                                                  const float* __restrict__ bo, float* __restrict__ out, int T) {
  __shared__ float As[16][68];
  __shared__ float Bs[16][96];
  int tid = threadIdx.x;
  int tx = tid & 15, ty = tid >> 4;
  int row0 = blockIdx.x * 64;
  float acc[4][6] = {};
  for (int k0 = 0; k0 < 512; k0 += 16) {
    {
      int r = tid >> 2;
      int kk = (tid & 3) * 4;
      float4 v = *(const float4*)(h_hist + (size_t)(row0 + r) * 512 + k0 + kk);
      As[kk + 0][r] = v.x; As[kk + 1][r] = v.y; As[kk + 2][r] = v.z; As[kk + 3][r] = v.w;
    }
#pragma unroll
    for (int i = 0; i < 6; i++) {
      int e = tid + 256 * i;
      int kb = e / 96, n = e - kb * 96;
      Bs[kb][n] = WoT[(size_t)(k0 + kb) * 96 + n];
    }
    __syncthreads();
#pragma unroll
    for (int q = 0; q < 16; q++) {
      float av[4], bvv[6];
#pragma unroll
      for (int i = 0; i < 4; i++) av[i] = As[q][ty * 4 + i];
#pragma unroll
      for (int j = 0; j < 6; j++) bvv[j] = Bs[q][tx * 6 + j];
#pragma unroll
      for (int i = 0; i < 4; i++)
#pragma unroll
        for (int j = 0; j < 6; j++) acc[i][j] += av[i] * bvv[j];
    }
    __syncthreads();
  }
#pragma unroll
  for (int i = 0; i < 4; i++)
#pragma unroll
    for (int j = 0; j < 6; j++) {
      int row = row0 + ty * 4 + i;
      int tt = row >> 9, bb = row & 511;
      int cc = tx * 6 + j;
      out[((size_t)bb * T + tt) * 96 + cc] = acc[i][j] + bo[cc];
    }
}

extern "C" void kernel_launch(void* const* d_in, const int* in_sizes, int n_in,
                              void* d_out, int out_size, void* d_ws, size_t ws_size,
                              hipStream_t stream) {
  const float* features  = (const float*)d_in[0];
  const int*   targets   = (const int*)d_in[1];
  const float* Wfc       = (const float*)d_in[3];
  const float* bfc       = (const float*)d_in[4];
  const float* emb_table = (const float*)d_in[5];
  const float* Wa        = (const float*)d_in[6];
  const float* ba        = (const float*)d_in[7];
  const float* Wc        = (const float*)d_in[8];
  const float* bc        = (const float*)d_in[9];
  const float* Wih       = (const float*)d_in[10];
  const float* Whh       = (const float*)d_in[11];
  const float* bih       = (const float*)d_in[12];
  const float* bhh       = (const float*)d_in[13];
  const float* Wo        = (const float*)d_in[14];
  const float* bo        = (const float*)d_in[15];
  float* out = (float*)d_out;
  int T = in_sizes[1] / BATCH;  // 30

  float* ws = (float*)d_ws;
  float* feats   = ws; ws += (size_t)BATCH * PPOS * HIDC;   // 16.8M
  float* WfcT    = ws; ws += 512 * 512;
  float* WaT_h   = ws; ws += 512 * 512;
  float* WaT_emb = ws; ws += 512 * 512;
  float* WcT     = ws; ws += 1024 * 512;
  float* WihT    = ws; ws += 512 * 2048;
  float* tmp     = ws; ws += (size_t)1024 * 2048;           // Wbig^T
  float* Bcat    = ws; ws += (size_t)1024 * 2048;           // gate-interleaved
  float* Gemb_p  = ws; ws += 96 * 2048;
  float* Za      = ws; ws += 96 * 512;
  float* bfused  = ws; ws += 2048;
  float* WoT     = ws; ws += 512 * 96;
  float* h0      = ws; ws += BATCH * HIDC;
  float* cbuf    = ws; ws += BATCH * HIDC;
  float* ctx     = ws; ws += BATCH * HIDC;
  float* h_hist  = ws; ws += (size_t)T * BATCH * HIDC;      // 7.9M

  dim3 tb(32, 8);
  transpose_k<<<dim3(16, 16), tb, 0, stream>>>(Wfc, WfcT, 512, 512, 512);
  transpose_k<<<dim3(16, 16), tb, 0, stream>>>(Wa, WaT_h, 512, 512, 1024);
  transpose_k<<<dim3(16, 16), tb, 0, stream>>>(Wa + 512, WaT_emb, 512, 512, 1024);
  transpose_k<<<dim3(32, 16), tb, 0, stream>>>(Wc, WcT, 512, 1024, 1024);
  transpose_k<<<dim3(16, 64), tb, 0, stream>>>(Wih, WihT, 2048, 512, 512);
  transpose_k<<<dim3(16, 3),  tb, 0, stream>>>(Wo, WoT, 96, 512, 512);

  // tmp = WcT[1024x512] @ WihT[512x2048]  ( = (Wih@Wc)^T )
  gemm64_k<false><<<dim3(32, 16), 256, 0, stream>>>(WcT, WihT, nullptr, tmp, 1024, 2048, 512);
  bfuse_k<<<8, 256, 0, stream>>>(Wih, bc, bih, bhh, bfused);
  build_bcat_k<<<(1024 * 2048) / 256, 256, 0, stream>>>(tmp, Whh, Bcat);
  gemb_k<<<dim3(8, 24), 256, 0, stream>>>(emb_table, tmp, bfused, Gemb_p);
  za_k<<<dim3(2, 24), 256, 0, stream>>>(emb_table, WaT_emb, ba, Za);

  // feats = features @ Wfc.T + bfc   [32768 x 512]
  gemm64_k<true><<<dim3(8, 512), 256, 0, stream>>>(features, WfcT, bfc, feats, 32768, 512, 512);

  hipMemsetAsync(h0, 0, (size_t)BATCH * HIDC * sizeof(float), stream);
  hipMemsetAsync(cbuf, 0, (size_t)BATCH * HIDC * sizeof(float), stream);

  for (int t = 0; t < T; t++) {
    const float* h_prev = (t == 0) ? h0 : (h_hist + (size_t)(t - 1) * BATCH * HIDC);
    float* h_new = h_hist + (size_t)t * BATCH * HIDC;
    attn_fused_k<<<256, 512, 0, stream>>>(h_prev, targets, t, T, WaT_h, Za, feats, ctx);
    gates_lstm_k<<<dim3(32, 8), 256, 0, stream>>>(ctx, h_prev, targets, t, T, Bcat, Gemb_p, cbuf, h_new);
  }
  out_gemm_k<<<(T * BATCH) / 64, 256, 0, stream>>>(h_hist, WoT, bo, out, T);
}

// Round 4
// 2099.264 us; speedup vs baseline: 3.4720x; 1.4661x over previous
//
#include <hip/hip_runtime.h>
#include <math.h>

// AttentionOCR: B=512, P=64, CIN=512, HID=512, EMB=512, NCLS=96, T=30
static constexpr int BATCH = 512;
static constexpr int PPOS  = 64;
static constexpr int HIDC  = 512;

typedef __attribute__((ext_vector_type(8))) short bf8;   // 8 bf16 = 4 VGPRs (guide §3)
typedef __attribute__((ext_vector_type(4))) float f4;

static __device__ __forceinline__ float sigmoidf_(float x) { return 1.f / (1.f + expf(-x)); }

static __device__ __forceinline__ short f2bf(float x) {
  unsigned u = __float_as_uint(x);
  u = u + 0x7FFF + ((u >> 16) & 1);   // round-nearest-even to bf16
  return (short)(u >> 16);
}
static __device__ __forceinline__ float bf2f(short s) {
  return __uint_as_float(((unsigned)(unsigned short)s) << 16);
}

// ---------------- strided transpose: dst[C x R], dst[c][r] = src[r*ld + c] ----------------
__global__ void transpose_k(const float* __restrict__ src, float* __restrict__ dst, int R, int C, int ld) {
  __shared__ float tile[32][33];
  int c0 = blockIdx.x * 32, r0 = blockIdx.y * 32;
  int x = threadIdx.x;
  for (int yy = threadIdx.y; yy < 32; yy += 8) {
    int r = r0 + yy, c = c0 + x;
    if (r < R && c < C) tile[yy][x] = src[(size_t)r * ld + c];
  }
  __syncthreads();
  for (int yy = threadIdx.y; yy < 32; yy += 8) {
    int c = c0 + yy, r = r0 + x;
    if (r < R && c < C) dst[(size_t)c * R + r] = tile[x][yy];
  }
}

// ---- fp32 GEMM (setup only): C[MxN]=A[MxK]@B[KxN](+bias), dbuf, 1 barrier/tile ----
template <bool BIAS>
__global__ __launch_bounds__(256) void gemm64_k(const float* __restrict__ A, const float* __restrict__ Bm,
                                                const float* __restrict__ bias, float* __restrict__ C,
                                                int M, int N, int K) {
  __shared__ float As[2][16][68];
  __shared__ float Bs[2][16][64];
  int tid = threadIdx.x;
  int tx = tid & 15, ty = tid >> 4;
  int row0 = blockIdx.y * 64, col0 = blockIdx.x * 64;
  int ar = tid >> 2, ak = (tid & 3) * 4;
  int bkb = tid >> 4, bn = (tid & 15) * 4;
  const float* Aptr = A + (size_t)(row0 + ar) * K + ak;
  const float* Bptr = Bm + (size_t)bkb * N + col0 + bn;
  float4 av = *(const float4*)Aptr;
  float4 bv = *(const float4*)Bptr;
  float acc[4][4] = {};
  int NT = K / 16;
  for (int kt = 0; kt < NT; kt++) {
    int buf = kt & 1;
    As[buf][ak + 0][ar] = av.x; As[buf][ak + 1][ar] = av.y;
    As[buf][ak + 2][ar] = av.z; As[buf][ak + 3][ar] = av.w;
    *(float4*)&Bs[buf][bkb][bn] = bv;
    if (kt + 1 < NT) {
      Aptr += 16; Bptr += (size_t)16 * N;
      av = *(const float4*)Aptr;
      bv = *(const float4*)Bptr;
    }
    __syncthreads();
#pragma unroll
    for (int q = 0; q < 16; q++) {
      float4 a4 = *(const float4*)&As[buf][q][ty * 4];
      float4 b4 = *(const float4*)&Bs[buf][q][tx * 4];
      acc[0][0] += a4.x * b4.x; acc[0][1] += a4.x * b4.y; acc[0][2] += a4.x * b4.z; acc[0][3] += a4.x * b4.w;
      acc[1][0] += a4.y * b4.x; acc[1][1] += a4.y * b4.y; acc[1][2] += a4.y * b4.z; acc[1][3] += a4.y * b4.w;
      acc[2][0] += a4.z * b4.x; acc[2][1] += a4.z * b4.y; acc[2][2] += a4.z * b4.z; acc[2][3] += a4.z * b4.w;
      acc[3][0] += a4.w * b4.x; acc[3][1] += a4.w * b4.y; acc[3][2] += a4.w * b4.z; acc[3][3] += a4.w * b4.w;
    }
  }
#pragma unroll
  for (int i = 0; i < 4; i++)
#pragma unroll
    for (int j = 0; j < 4; j++) {
      int rr = row0 + ty * 4 + i, cc = col0 + tx * 4 + j;
      float v = acc[i][j];
      if (BIAS) v += bias[cc];
      C[(size_t)rr * N + cc] = v;
    }
}

// ---------------- bfused[n] = bih[n] + bhh[n] + dot(Wih[n,:], bc) ----------------
__global__ void bfuse_k(const float* __restrict__ Wih, const float* __restrict__ bc,
                        const float* __restrict__ bih, const float* __restrict__ bhh,
                        float* __restrict__ bf) {
  int n = blockIdx.x * 256 + threadIdx.x;  // < 2048
  float s = bih[n] + bhh[n];
  const float* w = Wih + (size_t)n * 512;
  for (int m = 0; m < 512; m++) s += w[m] * bc[m];
  bf[n] = s;
}

// ---- BTg[2048 cp][1024 k] bf16 hi/lo: BTg[cp][k] = Bcat[k][cp], cp = j*4+g gate-interleaved ----
__global__ void build_btg_k(const float* __restrict__ tmp, const float* __restrict__ Whh,
                            short* __restrict__ hi, short* __restrict__ lo) {
  int idx = blockIdx.x * 256 + threadIdx.x;  // < 2048*1024
  int cp = idx >> 10, k = idx & 1023;
  int j = cp >> 2, g = cp & 3;
  int n = g * 512 + j;
  float v = (k < 512) ? tmp[(size_t)(512 + k) * 2048 + n] : Whh[(size_t)n * 512 + (k - 512)];
  short h = f2bf(v);
  hi[idx] = h;
  lo[idx] = f2bf(v - bf2f(h));
}

// ---- split fp32 -> bf16 hi/lo ----
__global__ void split_k(const float* __restrict__ src, short* __restrict__ hi, short* __restrict__ lo, int n) {
  int i = blockIdx.x * 256 + threadIdx.x;
  if (i < n) {
    float x = src[i];
    short h = f2bf(x);
    hi[i] = h;
    lo[i] = f2bf(x - bf2f(h));
  }
}

// ---------------- Gemb_p[96 x 2048] = (emb_table @ tmp[0:512]) + bfused, columns permuted ----------------
__global__ __launch_bounds__(256) void gemb_k(const float* __restrict__ emb_table, const float* __restrict__ tmp,
                                              const float* __restrict__ bfused, float* __restrict__ Gemb_p) {
  __shared__ float emb_s[4][512];
  int tid = threadIdx.x;
  int n0 = blockIdx.x * 256;
  int e0 = blockIdx.y * 4;
  for (int i = tid; i < 2048; i += 256)
    emb_s[i >> 9][i & 511] = emb_table[(size_t)(e0 + (i >> 9)) * 512 + (i & 511)];
  __syncthreads();
  int n = n0 + tid;
  float acc[4] = {};
  for (int k = 0; k < 512; k++) {
    float w = tmp[(size_t)k * 2048 + n];
#pragma unroll
    for (int e = 0; e < 4; e++) acc[e] += emb_s[e][k] * w;
  }
  int cp = (n & 511) * 4 + (n >> 9);
  float b = bfused[n];
#pragma unroll
  for (int e = 0; e < 4; e++) Gemb_p[(size_t)(e0 + e) * 2048 + cp] = acc[e] + b;
}

// ---------------- Za[96 x 512] = emb_table @ WaT_emb + ba ----------------
__global__ __launch_bounds__(256) void za_k(const float* __restrict__ emb_table, const float* __restrict__ WaT_emb,
                                            const float* __restrict__ ba, float* __restrict__ Za) {
  __shared__ float emb_s[4][512];
  int tid = threadIdx.x;
  int n0 = blockIdx.x * 256;
  int e0 = blockIdx.y * 4;
  for (int i = tid; i < 2048; i += 256)
    emb_s[i >> 9][i & 511] = emb_table[(size_t)(e0 + (i >> 9)) * 512 + (i & 511)];
  __syncthreads();
  int n = n0 + tid;
  float acc[4] = {};
  for (int k = 0; k < 512; k++) {
    float w = WaT_emb[(size_t)k * 512 + n];
#pragma unroll
    for (int e = 0; e < 4; e++) acc[e] += emb_s[e][k] * w;
  }
  float b = ba[n];
#pragma unroll
  for (int e = 0; e < 4; e++) Za[(size_t)(e0 + e) * 512 + n] = acc[e] + b;
}

// ---------------- fused attention step (unchanged, validated) ----------------
__global__ __launch_bounds__(512) void attn_fused_k(const float* __restrict__ h_prev,
                                                    const int* __restrict__ targets, int t, int T,
                                                    const float* __restrict__ WaT_h, const float* __restrict__ Za,
                                                    const float* __restrict__ feats, float* __restrict__ ctx) {
  __shared__ __align__(16) float h_s[2][512];
  __shared__ __align__(16) float zred[4][2][512];
  __shared__ __align__(16) float z_s[2][512];
  __shared__ float redm[8], reds[8];
  __shared__ float sc_s[2][64];
  __shared__ float w_s[2][64];
  int tid = threadIdx.x;
  int wid = tid >> 6, lane = tid & 63;
  int b0 = blockIdx.x * 2;
  int id0 = (t == 0) ? 0 : targets[b0 * T + t - 1];
  int id1 = (t == 0) ? 0 : targets[(b0 + 1) * T + t - 1];
  for (int i = tid; i < 1024; i += 512)
    h_s[i >> 9][i & 511] = h_prev[(size_t)(b0 + (i >> 9)) * 512 + (i & 511)];
  __syncthreads();

  {
    int nq = tid & 127, ks = tid >> 7;
    int n0 = nq * 4;
    const float* wb = WaT_h + (size_t)(ks * 128) * 512 + n0;
    float a00 = 0.f, a01 = 0.f, a02 = 0.f, a03 = 0.f;
    float a10 = 0.f, a11 = 0.f, a12 = 0.f, a13 = 0.f;
#pragma unroll 4
    for (int k = 0; k < 128; k++) {
      float4 w = *(const float4*)(wb + (size_t)k * 512);
      float hv0 = h_s[0][ks * 128 + k];
      float hv1 = h_s[1][ks * 128 + k];
      a00 += hv0 * w.x; a01 += hv0 * w.y; a02 += hv0 * w.z; a03 += hv0 * w.w;
      a10 += hv1 * w.x; a11 += hv1 * w.y; a12 += hv1 * w.z; a13 += hv1 * w.w;
    }
    *(float4*)&zred[ks][0][n0] = make_float4(a00, a01, a02, a03);
    *(float4*)&zred[ks][1][n0] = make_float4(a10, a11, a12, a13);
  }
  __syncthreads();

  {
    int r = tid >> 8;
    int nn = tid & 255;
    int idr = r ? id1 : id0;
    float zv0 = Za[(size_t)idr * 512 + nn]
              + zred[0][r][nn] + zred[1][r][nn] + zred[2][r][nn] + zred[3][r][nn];
    float zv1 = Za[(size_t)idr * 512 + nn + 256]
              + zred[0][r][nn + 256] + zred[1][r][nn + 256] + zred[2][r][nn + 256] + zred[3][r][nn + 256];
    float m = fmaxf(zv0, zv1);
#pragma unroll
    for (int off = 32; off; off >>= 1) m = fmaxf(m, __shfl_xor(m, off, 64));
    if (lane == 0) redm[wid] = m;
    __syncthreads();
    float M = fmaxf(fmaxf(redm[r * 4], redm[r * 4 + 1]), fmaxf(redm[r * 4 + 2], redm[r * 4 + 3]));
    float e0 = expf(zv0 - M), e1 = expf(zv1 - M);
    float s = e0 + e1;
#pragma unroll
    for (int off = 32; off; off >>= 1) s += __shfl_xor(s, off, 64);
    if (lane == 0) reds[wid] = s;
    __syncthreads();
    float S = reds[r * 4] + reds[r * 4 + 1] + reds[r * 4 + 2] + reds[r * 4 + 3];
    float inv = 1.f / S;
    z_s[r][nn] = e0 * inv;
    z_s[r][nn + 256] = e1 * inv;
  }
  __syncthreads();

#pragma unroll 1
  for (int q = 0; q < 16; q++) {
    int task = wid * 16 + q;
    int r = task >> 6, p = task & 63;
    const float4* fp = (const float4*)(feats + ((size_t)(b0 + r) * PPOS + p) * 512);
    const float4* ap = (const float4*)(z_s[r]);
    float4 f1 = fp[lane], a1 = ap[lane];
    float4 f2 = fp[lane + 64], a2 = ap[lane + 64];
    float d = f1.x * a1.x + f1.y * a1.y + f1.z * a1.z + f1.w * a1.w
            + f2.x * a2.x + f2.y * a2.y + f2.z * a2.z + f2.w * a2.w;
#pragma unroll
    for (int off = 32; off; off >>= 1) d += __shfl_xor(d, off, 64);
    if (lane == 0) sc_s[r][p] = d;
  }
  __syncthreads();

  if (tid < 128) {
    int r = wid;
    float v = sc_s[r][lane];
    float m = v;
#pragma unroll
    for (int off = 32; off; off >>= 1) m = fmaxf(m, __shfl_xor(m, off, 64));
    float e = expf(v - m);
    float s = e;
#pragma unroll
    for (int off = 32; off; off >>= 1) s += __shfl_xor(s, off, 64);
    w_s[r][lane] = e / s;
  }
  __syncthreads();

#pragma unroll 1
  for (int r = 0; r < 2; r++) {
    const float* fb = feats + (size_t)(b0 + r) * PPOS * 512 + tid;
    float acc = 0.f;
#pragma unroll 8
    for (int p = 0; p < 64; p++) acc += w_s[r][p] * fb[(size_t)p * 512];
    ctx[(size_t)(b0 + r) * 512 + tid] = acc;
  }
}

// ================= MFMA split-bf16 GEMMs =================
// C = A@B via A_hi@B_hi + A_lo@B_hi + A_hi@B_lo (lo*lo dropped, ~2^-18 rel).
// 64x64 block tile, 4 waves (2x2), each wave 2x2 mfma_f32_16x16x32_bf16 tiles.
// LDS tiles [64][40] bf16 (pad 40 -> b128 frag reads hit all 32 banks).
// A staged from fp32 with on-the-fly hi/lo split; B pre-split as B^T[n][k] bf16.

// ---- feats: C[32768x512] = features[32768x512] @ Wfc^T (+bfc). BT = Wfc itself. ----
__global__ __launch_bounds__(256) void feats_mfma_k(const float* __restrict__ A,
                                                    const short* __restrict__ BTh, const short* __restrict__ BTl,
                                                    const float* __restrict__ bias, float* __restrict__ C) {
  __shared__ short Ah[2][64][40], Al[2][64][40], Bh[2][64][40], Bl[2][64][40];
  int tid = threadIdx.x;
  int lane = tid & 63, wave = tid >> 6;
  int wm = (wave & 1) * 32, wn = (wave >> 1) * 32;
  int r15 = lane & 15, q8 = (lane >> 4) * 8;
  int row0 = blockIdx.y * 64, col0 = blockIdx.x * 64;
  int sm = tid >> 2, sk = (tid & 3) * 8;
  const float* Ap = A + (size_t)(row0 + sm) * 512 + sk;
  const short* Bhp = BTh + (size_t)(col0 + sm) * 512 + sk;
  const short* Blp = BTl + (size_t)(col0 + sm) * 512 + sk;
  float4 a0 = *(const float4*)Ap, a1 = *(const float4*)(Ap + 4);
  bf8 bh = *(const bf8*)Bhp, bl = *(const bf8*)Blp;
  f4 acc[2][2] = {};
  for (int kt = 0; kt < 16; kt++) {
    int buf = kt & 1;
    {
      float av[8] = {a0.x, a0.y, a0.z, a0.w, a1.x, a1.y, a1.z, a1.w};
      bf8 ahv, alv;
#pragma unroll
      for (int i = 0; i < 8; i++) {
        short h = f2bf(av[i]);
        ahv[i] = h;
        alv[i] = f2bf(av[i] - bf2f(h));
      }
      *(bf8*)&Ah[buf][sm][sk] = ahv;
      *(bf8*)&Al[buf][sm][sk] = alv;
      *(bf8*)&Bh[buf][sm][sk] = bh;
      *(bf8*)&Bl[buf][sm][sk] = bl;
    }
    if (kt + 1 < 16) {
      Ap += 32; Bhp += 32; Blp += 32;
      a0 = *(const float4*)Ap; a1 = *(const float4*)(Ap + 4);
      bh = *(const bf8*)Bhp; bl = *(const bf8*)Blp;
    }
    __syncthreads();
    bf8 fah[2], fal[2], fbh[2], fbl[2];
#pragma unroll
    for (int r = 0; r < 2; r++) {
      fah[r] = *(const bf8*)&Ah[buf][wm + r * 16 + r15][q8];
      fal[r] = *(const bf8*)&Al[buf][wm + r * 16 + r15][q8];
    }
#pragma unroll
    for (int c = 0; c < 2; c++) {
      fbh[c] = *(const bf8*)&Bh[buf][wn + c * 16 + r15][q8];
      fbl[c] = *(const bf8*)&Bl[buf][wn + c * 16 + r15][q8];
    }
#pragma unroll
    for (int r = 0; r < 2; r++)
#pragma unroll
      for (int c = 0; c < 2; c++) {
        acc[r][c] = __builtin_amdgcn_mfma_f32_16x16x32_bf16(fah[r], fbh[c], acc[r][c], 0, 0, 0);
        acc[r][c] = __builtin_amdgcn_mfma_f32_16x16x32_bf16(fal[r], fbh[c], acc[r][c], 0, 0, 0);
        acc[r][c] = __builtin_amdgcn_mfma_f32_16x16x32_bf16(fah[r], fbl[c], acc[r][c], 0, 0, 0);
      }
  }
#pragma unroll
  for (int r = 0; r < 2; r++)
#pragma unroll
    for (int c = 0; c < 2; c++) {
      int col = col0 + wn + c * 16 + r15;
      float bv = bias[col];
#pragma unroll
      for (int i = 0; i < 4; i++) {
        int row = row0 + wm + r * 16 + (lane >> 4) * 4 + i;
        C[(size_t)row * 512 + col] = acc[r][c][i] + bv;
      }
    }
}

// ---- gates: [ctx|h][512x1024] @ Bcat[1024x2048] (+Gemb[id]) -> LSTM pointwise ----
__global__ __launch_bounds__(256) void gates_mfma_k(const float* __restrict__ ctx, const float* __restrict__ h_prev,
                                                    const int* __restrict__ targets, int t, int T,
                                                    const short* __restrict__ BTh, const short* __restrict__ BTl,
                                                    const float* __restrict__ Gemb_p,
                                                    float* __restrict__ cbuf, float* __restrict__ h_new) {
  __shared__ short Ah[2][64][40], Al[2][64][40], Bh[2][64][40], Bl[2][64][40];
  __shared__ float Cs[64][68];
  int tid = threadIdx.x;
  int lane = tid & 63, wave = tid >> 6;
  int wm = (wave & 1) * 32, wn = (wave >> 1) * 32;
  int r15 = lane & 15, q8 = (lane >> 4) * 8;
  int row0 = blockIdx.y * 64, col0 = blockIdx.x * 64;
  int sm = tid >> 2, sk = (tid & 3) * 8;
  const float* actx = ctx + (size_t)(row0 + sm) * 512;
  const float* ahst = h_prev + (size_t)(row0 + sm) * 512;
  const short* Bhp = BTh + (size_t)(col0 + sm) * 1024 + sk;
  const short* Blp = BTl + (size_t)(col0 + sm) * 1024 + sk;
  float4 a0 = *(const float4*)(actx + sk), a1 = *(const float4*)(actx + sk + 4);
  bf8 bh = *(const bf8*)Bhp, bl = *(const bf8*)Blp;
  f4 acc[2][2] = {};
  for (int kt = 0; kt < 32; kt++) {
    int buf = kt & 1;
    {
      float av[8] = {a0.x, a0.y, a0.z, a0.w, a1.x, a1.y, a1.z, a1.w};
      bf8 ahv, alv;
#pragma unroll
      for (int i = 0; i < 8; i++) {
        short h = f2bf(av[i]);
        ahv[i] = h;
        alv[i] = f2bf(av[i] - bf2f(h));
      }
      *(bf8*)&Ah[buf][sm][sk] = ahv;
      *(bf8*)&Al[buf][sm][sk] = alv;
      *(bf8*)&Bh[buf][sm][sk] = bh;
      *(bf8*)&Bl[buf][sm][sk] = bl;
    }
    if (kt + 1 < 32) {
      int kk = (kt + 1) * 32 + sk;
      const float* s = (kk < 512) ? (actx + kk) : (ahst + kk - 512);
      a0 = *(const float4*)s; a1 = *(const float4*)(s + 4);
      Bhp += 32; Blp += 32;
      bh = *(const bf8*)Bhp; bl = *(const bf8*)Blp;
    }
    __syncthreads();
    bf8 fah[2], fal[2], fbh[2], fbl[2];
#pragma unroll
    for (int r = 0; r < 2; r++) {
      fah[r] = *(const bf8*)&Ah[buf][wm + r * 16 + r15][q8];
      fal[r] = *(const bf8*)&Al[buf][wm + r * 16 + r15][q8];
    }
#pragma unroll
    for (int c = 0; c < 2; c++) {
      fbh[c] = *(const bf8*)&Bh[buf][wn + c * 16 + r15][q8];
      fbl[c] = *(const bf8*)&Bl[buf][wn + c * 16 + r15][q8];
    }
#pragma unroll
    for (int r = 0; r < 2; r++)
#pragma unroll
      for (int c = 0; c < 2; c++) {
        acc[r][c] = __builtin_amdgcn_mfma_f32_16x16x32_bf16(fah[r], fbh[c], acc[r][c], 0, 0, 0);
        acc[r][c] = __builtin_amdgcn_mfma_f32_16x16x32_bf16(fal[r], fbh[c], acc[r][c], 0, 0, 0);
        acc[r][c] = __builtin_amdgcn_mfma_f32_16x16x32_bf16(fah[r], fbl[c], acc[r][c], 0, 0, 0);
      }
  }
  // stage C tile to LDS (MFMA C layout -> row/col), then LSTM epilogue
#pragma unroll
  for (int r = 0; r < 2; r++)
#pragma unroll
    for (int c = 0; c < 2; c++)
#pragma unroll
      for (int i = 0; i < 4; i++)
        Cs[wm + r * 16 + (lane >> 4) * 4 + i][wn + c * 16 + r15] = acc[r][c][i];
  __syncthreads();
#pragma unroll
  for (int i = 0; i < 4; i++) {
    int idx = i * 256 + tid;
    int row = idx >> 4, jj = idx & 15;
    int b = row0 + row;
    int jg = (col0 >> 2) + jj;
    int id = (t == 0) ? 0 : targets[b * T + t - 1];
    float4 g4 = *(const float4*)(Gemb_p + (size_t)id * 2048 + col0 + jj * 4);
    float ig = sigmoidf_(Cs[row][jj * 4 + 0] + g4.x);
    float fg = sigmoidf_(Cs[row][jj * 4 + 1] + g4.y);
    float gg = tanhf(Cs[row][jj * 4 + 2] + g4.z);
    float og = sigmoidf_(Cs[row][jj * 4 + 3] + g4.w);
    float cn = fg * cbuf[(size_t)b * 512 + jg] + ig * gg;
    float hn = og * tanhf(cn);
    cbuf[(size_t)b * 512 + jg] = cn;
    h_new[(size_t)b * 512 + jg] = hn;
  }
}

// ---------------- final output GEMM over all timesteps ----------------
__global__ __launch_bounds__(256) void out_gemm_k(const float* __restrict__ h_hist, const float* __restrict__ WoT,
                                                  const float* __restrict__ bo, float* __restrict__ out, int T) {
  __shared__ float As[16][68];
  __shared__ float Bs[16][96];
  int tid = threadIdx.x;
  int tx = tid & 15, ty = tid >> 4;
  int row0 = blockIdx.x * 64;
  float acc[4][6] = {};
  for (int k0 = 0; k0 < 512; k0 += 16) {
    {
      int r = tid >> 2;
      int kk = (tid & 3) * 4;
      float4 v = *(const float4*)(h_hist + (size_t)(row0 + r) * 512 + k0 + kk);
      As[kk + 0][r] = v.x; As[kk + 1][r] = v.y; As[kk + 2][r] = v.z; As[kk + 3][r] = v.w;
    }
#pragma unroll
    for (int i = 0; i < 6; i++) {
      int e = tid + 256 * i;
      int kb = e / 96, n = e - kb * 96;
      Bs[kb][n] = WoT[(size_t)(k0 + kb) * 96 + n];
    }
    __syncthreads();
#pragma unroll
    for (int q = 0; q < 16; q++) {
      float av[4], bvv[6];
#pragma unroll
      for (int i = 0; i < 4; i++) av[i] = As[q][ty * 4 + i];
#pragma unroll
      for (int j = 0; j < 6; j++) bvv[j] = Bs[q][tx * 6 + j];
#pragma unroll
      for (int i = 0; i < 4; i++)
#pragma unroll
        for (int j = 0; j < 6; j++) acc[i][j] += av[i] * bvv[j];
    }
    __syncthreads();
  }
#pragma unroll
  for (int i = 0; i < 4; i++)
#pragma unroll
    for (int j = 0; j < 6; j++) {
      int row = row0 + ty * 4 + i;
      int tt = row >> 9, bb = row & 511;
      int cc = tx * 6 + j;
      out[((size_t)bb * T + tt) * 96 + cc] = acc[i][j] + bo[cc];
    }
}

extern "C" void kernel_launch(void* const* d_in, const int* in_sizes, int n_in,
                              void* d_out, int out_size, void* d_ws, size_t ws_size,
                              hipStream_t stream) {
  const float* features  = (const float*)d_in[0];
  const int*   targets   = (const int*)d_in[1];
  const float* Wfc       = (const float*)d_in[3];
  const float* bfc       = (const float*)d_in[4];
  const float* emb_table = (const float*)d_in[5];
  const float* Wa        = (const float*)d_in[6];
  const float* ba        = (const float*)d_in[7];
  const float* Wc        = (const float*)d_in[8];
  const float* bc        = (const float*)d_in[9];
  const float* Wih       = (const float*)d_in[10];
  const float* Whh       = (const float*)d_in[11];
  const float* bih       = (const float*)d_in[12];
  const float* bhh       = (const float*)d_in[13];
  const float* Wo        = (const float*)d_in[14];
  const float* bo        = (const float*)d_in[15];
  float* out = (float*)d_out;
  int T = in_sizes[1] / BATCH;  // 30

  char* base = (char*)d_ws;
  auto alloc = [&](size_t bytes) -> char* {
    char* p = base;
    base += (bytes + 255) & ~(size_t)255;
    return p;
  };
  float* feats   = (float*)alloc((size_t)BATCH * PPOS * HIDC * 4);
  float* WaT_h   = (float*)alloc(512 * 512 * 4);
  float* WaT_emb = (float*)alloc(512 * 512 * 4);
  float* WcT     = (float*)alloc(1024 * 512 * 4);
  float* WihT    = (float*)alloc(512 * 2048 * 4);
  float* tmp     = (float*)alloc((size_t)1024 * 2048 * 4);
  short* BTg_hi  = (short*)alloc((size_t)2048 * 1024 * 2);
  short* BTg_lo  = (short*)alloc((size_t)2048 * 1024 * 2);
  short* Wfc_hi  = (short*)alloc(512 * 512 * 2);
  short* Wfc_lo  = (short*)alloc(512 * 512 * 2);
  float* Gemb_p  = (float*)alloc(96 * 2048 * 4);
  float* Za      = (float*)alloc(96 * 512 * 4);
  float* bfused  = (float*)alloc(2048 * 4);
  float* WoT     = (float*)alloc(512 * 96 * 4);
  float* h0      = (float*)alloc(BATCH * HIDC * 4);
  float* cbuf    = (float*)alloc(BATCH * HIDC * 4);
  float* ctx     = (float*)alloc(BATCH * HIDC * 4);
  float* h_hist  = (float*)alloc((size_t)T * BATCH * HIDC * 4);

  dim3 tb(32, 8);
  transpose_k<<<dim3(16, 16), tb, 0, stream>>>(Wa, WaT_h, 512, 512, 1024);
  transpose_k<<<dim3(16, 16), tb, 0, stream>>>(Wa + 512, WaT_emb, 512, 512, 1024);
  transpose_k<<<dim3(32, 16), tb, 0, stream>>>(Wc, WcT, 512, 1024, 1024);
  transpose_k<<<dim3(16, 64), tb, 0, stream>>>(Wih, WihT, 2048, 512, 512);
  transpose_k<<<dim3(16, 3),  tb, 0, stream>>>(Wo, WoT, 96, 512, 512);

  // tmp = WcT[1024x512] @ WihT[512x2048]  ( = (Wih@Wc)^T )
  gemm64_k<false><<<dim3(32, 16), 256, 0, stream>>>(WcT, WihT, nullptr, tmp, 1024, 2048, 512);
  bfuse_k<<<8, 256, 0, stream>>>(Wih, bc, bih, bhh, bfused);
  build_btg_k<<<(2048 * 1024) / 256, 256, 0, stream>>>(tmp, Whh, BTg_hi, BTg_lo);
  gemb_k<<<dim3(8, 24), 256, 0, stream>>>(emb_table, tmp, bfused, Gemb_p);
  za_k<<<dim3(2, 24), 256, 0, stream>>>(emb_table, WaT_emb, ba, Za);
  split_k<<<(512 * 512) / 256, 256, 0, stream>>>(Wfc, Wfc_hi, Wfc_lo, 512 * 512);

  // feats = features @ Wfc.T + bfc   [32768 x 512], split-bf16 MFMA
  feats_mfma_k<<<dim3(8, 512), 256, 0, stream>>>(features, Wfc_hi, Wfc_lo, bfc, feats);

  hipMemsetAsync(h0, 0, (size_t)BATCH * HIDC * 4, stream);
  hipMemsetAsync(cbuf, 0, (size_t)BATCH * HIDC * 4, stream);

  for (int t = 0; t < T; t++) {
    const float* h_prev = (t == 0) ? h0 : (h_hist + (size_t)(t - 1) * BATCH * HIDC);
    float* h_new = h_hist + (size_t)t * BATCH * HIDC;
    attn_fused_k<<<256, 512, 0, stream>>>(h_prev, targets, t, T, WaT_h, Za, feats, ctx);
    gates_mfma_k<<<dim3(32, 8), 256, 0, stream>>>(ctx, h_prev, targets, t, T, BTg_hi, BTg_lo, Gemb_p, cbuf, h_new);
  }
  out_gemm_k<<<(T * BATCH) / 64, 256, 0, stream>>>(h_hist, WoT, bo, out, T);
}